// Round 1
// baseline (135.575 us; speedup 1.0000x reference)
//
#include <hip/hip_runtime.h>
#include <cmath>

// Problem constants (Llama-3-8B down_proj decode GEMV with norm-based input mask)
#define ZDIM 14336
#define NDIM 4096
#define NT   256                 // threads per block
#define F4_PER_ROW (NDIM / 4)    // 1024 float4 per row
#define F4_PER_THR (F4_PER_ROW / NT)  // 4 float4 per thread per row
#define ROWS_PER_BLOCK 16
#define NBLOCKS (ZDIM / ROWS_PER_BLOCK)  // 896

// One-pass fused kernel:
//  - each block processes ROWS_PER_BLOCK consecutive rows of W_t
//  - per row: coalesced float4 load into registers, block-reduce sum-of-squares,
//    mask test, conditional FMA into per-thread register accumulators
//  - epilogue: atomicAdd partial y into global output
__global__ __launch_bounds__(NT) void masked_gemv_onepass(
    const float* __restrict__ x,
    const float* __restrict__ Wt,
    const float* __restrict__ thresh,
    float* __restrict__ y) {
  const int t    = threadIdx.x;
  const int lane = t & 63;
  const int wave = t >> 6;
  const int row0 = blockIdx.x * ROWS_PER_BLOCK;

  const float th = thresh[0];

  // parity-double-buffered per-wave partials: one barrier per row
  __shared__ float red[8];

  float acc[4 * F4_PER_THR];
  #pragma unroll
  for (int i = 0; i < 4 * F4_PER_THR; ++i) acc[i] = 0.0f;

  const float4* __restrict__ W4 = reinterpret_cast<const float4*>(Wt);

  for (int r = 0; r < ROWS_PER_BLOCK; ++r) {
    const int z = row0 + r;
    const float4* rowp = W4 + (size_t)z * F4_PER_ROW + t;

    // coalesced row load (held in registers, read exactly once from memory)
    float4 w[F4_PER_THR];
    #pragma unroll
    for (int k = 0; k < F4_PER_THR; ++k) w[k] = rowp[k * NT];

    // per-thread sum of squares
    float ss = 0.0f;
    #pragma unroll
    for (int k = 0; k < F4_PER_THR; ++k) {
      ss += w[k].x * w[k].x + w[k].y * w[k].y;
      ss += w[k].z * w[k].z + w[k].w * w[k].w;
    }

    // wave-64 butterfly reduce
    #pragma unroll
    for (int off = 32; off > 0; off >>= 1) ss += __shfl_down(ss, off, 64);

    const int par = (r & 1) << 2;
    if (lane == 0) red[wave + par] = ss;
    __syncthreads();
    const float norm2 = red[0 + par] + red[1 + par] + red[2 + par] + red[3 + par];

    const float xz = x[z];
    if (fabsf(xz) * sqrtf(norm2) >= th) {
      #pragma unroll
      for (int k = 0; k < F4_PER_THR; ++k) {
        acc[4 * k + 0] = fmaf(xz, w[k].x, acc[4 * k + 0]);
        acc[4 * k + 1] = fmaf(xz, w[k].y, acc[4 * k + 1]);
        acc[4 * k + 2] = fmaf(xz, w[k].z, acc[4 * k + 2]);
        acc[4 * k + 3] = fmaf(xz, w[k].w, acc[4 * k + 3]);
      }
    }
    // no second barrier needed: parity buffer isn't rewritten until after the
    // next iteration's barrier, which orders it after all reads above
  }

  // epilogue: accumulate block partials into global y (L2-resident, small)
  #pragma unroll
  for (int k = 0; k < F4_PER_THR; ++k) {
    const int n0 = (t + k * NT) * 4;
    atomicAdd(&y[n0 + 0], acc[4 * k + 0]);
    atomicAdd(&y[n0 + 1], acc[4 * k + 1]);
    atomicAdd(&y[n0 + 2], acc[4 * k + 2]);
    atomicAdd(&y[n0 + 3], acc[4 * k + 3]);
  }
}

extern "C" void kernel_launch(void* const* d_in, const int* in_sizes, int n_in,
                              void* d_out, int out_size, void* d_ws, size_t ws_size,
                              hipStream_t stream) {
  const float* x      = (const float*)d_in[0];  // [1,1,Z]
  const float* Wt     = (const float*)d_in[1];  // [Z,N]
  const float* thresh = (const float*)d_in[2];  // [1]
  float* y            = (float*)d_out;          // [1,1,N]

  // harness does NOT re-zero d_out between timed replays — zero it ourselves
  hipMemsetAsync(y, 0, (size_t)out_size * sizeof(float), stream);

  masked_gemv_onepass<<<NBLOCKS, NT, 0, stream>>>(x, Wt, thresh, y);
}